// Round 3
// baseline (1674.872 us; speedup 1.0000x reference)
//
#include <hip/hip_runtime.h>
#include <math.h>

// Problem constants (b=1 hard-coded)
#define H  24
#define NN 3072
#define D  128
#define G  16
#define BM 192
#define TOPK_K 896
#define PST 68             // P-tile LDS row stride (floats)
#define OUT2_OFF ((size_t)H * NN * D)
#define KV_HALF_BYTES ((size_t)H * NN * D * 2)   // 18874368
#define CSD_BYTES ((size_t)H * G * NN * 8)       // 9437184 (float64 cs)

// exp(s*scale) = exp2(s * scale * log2(e)); scale = 1/sqrt(128)
#define LOG2E_SCALE 0.12751743822f

typedef _Float16 half8 __attribute__((ext_vector_type(8)));
typedef _Float16 half4v __attribute__((ext_vector_type(4)));
typedef __fp16 fp16x2 __attribute__((ext_vector_type(2)));
typedef float floatx4 __attribute__((ext_vector_type(4)));

// async global->LDS, 16B per lane; LDS dest = wave-uniform base + lane*16 (HW rule)
#define GLOAD_LDS(g, l) __builtin_amdgcn_global_load_lds( \
    (const __attribute__((address_space(1))) void*)(g),   \
    (__attribute__((address_space(3))) void*)(l), 16, 0, 0)
#define WAITVM0() asm volatile("s_waitcnt vmcnt(0)" ::: "memory")

__device__ __forceinline__ floatx4 fzero4() {
  floatx4 z = {0.f, 0.f, 0.f, 0.f};
  return z;
}
// RTE pack (unbiased) — used for input fragments
__device__ __forceinline__ half8 pack_h8_rte(float4 a, float4 b) {
  half8 r;
  r[0] = (_Float16)a.x; r[1] = (_Float16)a.y; r[2] = (_Float16)a.z; r[3] = (_Float16)a.w;
  r[4] = (_Float16)b.x; r[5] = (_Float16)b.y; r[6] = (_Float16)b.z; r[7] = (_Float16)b.w;
  return r;
}
// RTZ packed cvt (1 instr per pair) — used for P (p>=0; small bias cancels in o - sp)
__device__ __forceinline__ half8 pack_h8_rtz(float4 a, float4 b) {
  fp16x2 h0 = __builtin_amdgcn_cvt_pkrtz(a.x, a.y);
  fp16x2 h1 = __builtin_amdgcn_cvt_pkrtz(a.z, a.w);
  fp16x2 h2 = __builtin_amdgcn_cvt_pkrtz(b.x, b.y);
  fp16x2 h3 = __builtin_amdgcn_cvt_pkrtz(b.z, b.w);
  half8 r;
  r[0] = (_Float16)h0[0]; r[1] = (_Float16)h0[1];
  r[2] = (_Float16)h1[0]; r[3] = (_Float16)h1[1];
  r[4] = (_Float16)h2[0]; r[5] = (_Float16)h2[1];
  r[6] = (_Float16)h3[0]; r[7] = (_Float16)h3[1];
  return r;
}
// residual: x - (float)f16(x)
__device__ __forceinline__ half8 pack_h8_residual(float4 a, float4 b, half8 hi) {
  float4 ra = make_float4(a.x - (float)hi[0], a.y - (float)hi[1],
                          a.z - (float)hi[2], a.w - (float)hi[3]);
  float4 rb = make_float4(b.x - (float)hi[4], b.y - (float)hi[5],
                          b.z - (float)hi[6], b.w - (float)hi[7]);
  return pack_h8_rte(ra, rb);
}

// ---------------- threefry2x32 (exact JAX semantics, validated round 1) ----------------
__device__ __forceinline__ void tf2x32(unsigned k0, unsigned k1, unsigned x0, unsigned x1,
                                       unsigned* o0, unsigned* o1) {
  unsigned ks2 = k0 ^ k1 ^ 0x1BD11BDAu;
  unsigned v0 = x0 + k0, v1 = x1 + k1;
#define TF_RND(r) { v0 += v1; v1 = (v1 << (r)) | (v1 >> (32 - (r))); v1 ^= v0; }
  TF_RND(13) TF_RND(15) TF_RND(26) TF_RND(6)   v0 += k1;  v1 += ks2 + 1u;
  TF_RND(17) TF_RND(29) TF_RND(16) TF_RND(24)  v0 += ks2; v1 += k0 + 2u;
  TF_RND(13) TF_RND(15) TF_RND(26) TF_RND(6)   v0 += k0;  v1 += k1 + 3u;
  TF_RND(17) TF_RND(29) TF_RND(16) TF_RND(24)  v0 += k1;  v1 += ks2 + 4u;
  TF_RND(13) TF_RND(15) TF_RND(26) TF_RND(6)   v0 += ks2; v1 += k0 + 5u;
#undef TF_RND
  *o0 = v0; *o1 = v1;
}

__global__ __launch_bounds__(256)
void rmask_kernel(float* __restrict__ mask) {
  const unsigned S = H * G * NN;
  unsigned i = blockIdx.x * 256u + threadIdx.x;
  if (i >= S) return;
  unsigned hb, lb, a, b;
  unsigned k1a, k1b, k2a, k2b;
  tf2x32(0u, 1u, 0u, 0u, &k1a, &k1b);
  tf2x32(0u, 1u, 0u, 1u, &k2a, &k2b);
  tf2x32(k1a, k1b, 0u, i, &a, &b); hb = a ^ b;
  tf2x32(k2a, k2b, 0u, i, &a, &b); lb = a ^ b;
  unsigned r = ((hb % 100u) * 96u + (lb % 100u)) % 100u;
  mask[i] = (r == 0u) ? 1.0f : 0.0f;
}

// ---------------- phase 0: k -> f16 hi + f16 residual (row-major) ----------------
__global__ __launch_bounds__(256)
void cvt_k_kernel(const float* __restrict__ k, _Float16* __restrict__ khi,
                  _Float16* __restrict__ klo) {
  size_t i = (size_t)blockIdx.x * 256 + threadIdx.x;   // 8 elems per thread
  const float4* src = (const float4*)k + i * 2;
  float4 a = src[0], b = src[1];
  half8 hi = pack_h8_rte(a, b);
  *(half8*)(khi + i * 8) = hi;
  *(half8*)(klo + i * 8) = pack_h8_residual(a, b, hi);
}

// ---------------- phase 0: v -> f16 transposed vT[h][d][key] ----------------
__global__ __launch_bounds__(256)
void cvt_vT_kernel(const float* __restrict__ v, _Float16* __restrict__ vT) {
  __shared__ _Float16 t[64][68];
  const int h = blockIdx.z, k0 = blockIdx.x * 64, d0 = blockIdx.y * 64;
  const int tid = threadIdx.x;
  const int c4 = tid & 15, r = tid >> 4;
#pragma unroll
  for (int i = 0; i < 4; ++i) {
    int row = r + i * 16;  // key row within tile
    float4 x = *(const float4*)(v + ((size_t)(h * NN + k0 + row)) * D + d0 + c4 * 4);
    t[c4 * 4 + 0][row] = (_Float16)x.x;
    t[c4 * 4 + 1][row] = (_Float16)x.y;
    t[c4 * 4 + 2][row] = (_Float16)x.z;
    t[c4 * 4 + 3][row] = (_Float16)x.w;
  }
  __syncthreads();
#pragma unroll
  for (int i = 0; i < 4; ++i) {
    int drow = r + i * 16;  // d within tile
    half4v val = *(const half4v*)&t[drow][c4 * 4];
    *(half4v*)(vT + (size_t)(h * D + d0 + drow) * NN + k0 + c4 * 4) = val;
  }
}

// ---------------- dense attention: R=32/wave, K-only LDS (single buffer), V direct ----------------
// 4 waves x 32 query rows = 128 rows/block, grid 576 (2 blocks/CU resident: 67 KB LDS).
// Each K-fragment b128 read now feeds 6 MFMAs (2 mt x 3 split terms) -> LDS bytes/FLOP halved.
// V fragments load direct from L2-resident vT (parallel VMEM pipe), batched 8-wide,
// issued before the exp phase so latency hides under VALU work (round-0-proven pattern).
// Single-buffer staging is race-free: end-of-iter barrier precedes next STAGE; the
// co-resident second block covers the stage latency via TLP.
__global__ __launch_bounds__(256, 2)
void dense_kernel(const float* __restrict__ q, const _Float16* __restrict__ khi_g,
                  const _Float16* __restrict__ klo_g, const _Float16* __restrict__ vT,
                  float* __restrict__ out, double* __restrict__ csb) {
  __shared__ __align__(16) _Float16 skK[2 * 8192];        // khi | klo, 32 KB
  __shared__ __align__(16) float p_sh[4][2][16 * PST];    // per-wave per-mt stripes, 34.8 KB
  const int tid = threadIdx.x;
  const int wave = tid >> 6, lane = tid & 63;
  const int l15 = lane & 15, l4 = lane >> 4;
  // XCD swizzle: 576 = 8 * 72, bijective
  const int wq = ((blockIdx.x & 7) * 72) + (blockIdx.x >> 3);
  const int h = wq / 24;
  const int m0 = (wq % 24) * 128;
  const int rowbase = m0 + wave * 32;
  const _Float16* khi = khi_g + (size_t)h * NN * D;
  const _Float16* klo = klo_g + (size_t)h * NN * D;
  const _Float16* vh = vT + (size_t)h * D * NN;

  // staging: 32 chunks of 1KB (chunks 0-15 khi rows 4c.., 16-31 klo). wave w: chunks w*8+i.
  // source col16 pre-swizzled: gc = l15 ^ (row & 7); LDS stays linear (gload_lds rule).
  const _Float16* ksrc = (wave < 2) ? khi : klo;
#define STAGE_K(kc_) {                                                          \
  _Pragma("unroll") for (int i_ = 0; i_ < 8; ++i_) {                            \
    int c_ = wave * 8 + i_;                                                     \
    int row_ = ((c_ & 15) * 4) + l4;                                            \
    int gc_ = l15 ^ (4 * (i_ & 1) + l4);                                        \
    GLOAD_LDS(ksrc + (size_t)((kc_) + row_) * D + gc_ * 8, &skK[c_ * 512]);     \
  } }

  // fragment read columns (same XOR as staged source)
  int kcol[4];
#pragma unroll
  for (int ds = 0; ds < 4; ++ds) kcol[ds] = ((ds * 4 + l4) ^ (l15 & 7)) * 8;

  // Q A-fragments hi+lo for 2 row tiles: A[m = mt*16 + l15][k = l4*8+j]
  half8 qh[2][4], ql[2][4];
#pragma unroll
  for (int mt = 0; mt < 2; ++mt)
#pragma unroll
    for (int ds = 0; ds < 4; ++ds) {
      const float* qp = q + ((size_t)(h * NN + rowbase + mt * 16 + l15)) * D + ds * 32 + l4 * 8;
      float4 a = *(const float4*)qp, b = *(const float4*)(qp + 4);
      qh[mt][ds] = pack_h8_rte(a, b);
      ql[mt][ds] = pack_h8_residual(a, b, qh[mt][ds]);
    }

  // ---- pass 1: row sums L (split-precision QK^T) ----
  float Lacc[2][4] = {{0.f, 0.f, 0.f, 0.f}, {0.f, 0.f, 0.f, 0.f}};
#pragma unroll 1
  for (int t = 0; t < 48; ++t) {
    STAGE_K(t * 64)
    WAITVM0();
    __builtin_amdgcn_s_barrier();
    floatx4 S[2][4];
#pragma unroll
    for (int mt = 0; mt < 2; ++mt)
#pragma unroll
      for (int nt = 0; nt < 4; ++nt) S[mt][nt] = fzero4();
#pragma unroll
    for (int nt = 0; nt < 4; ++nt) {
      const int rb = (nt * 16 + l15) * 128;
#pragma unroll
      for (int ds = 0; ds < 4; ++ds) {
        half8 kbh = *(const half8*)&skK[rb + kcol[ds]];
        half8 kbl = *(const half8*)&skK[8192 + rb + kcol[ds]];
        S[0][nt] = __builtin_amdgcn_mfma_f32_16x16x32_f16(qh[0][ds], kbh, S[0][nt], 0, 0, 0);
        S[1][nt] = __builtin_amdgcn_mfma_f32_16x16x32_f16(qh[1][ds], kbh, S[1][nt], 0, 0, 0);
        S[0][nt] = __builtin_amdgcn_mfma_f32_16x16x32_f16(qh[0][ds], kbl, S[0][nt], 0, 0, 0);
        S[1][nt] = __builtin_amdgcn_mfma_f32_16x16x32_f16(qh[1][ds], kbl, S[1][nt], 0, 0, 0);
        S[0][nt] = __builtin_amdgcn_mfma_f32_16x16x32_f16(ql[0][ds], kbh, S[0][nt], 0, 0, 0);
        S[1][nt] = __builtin_amdgcn_mfma_f32_16x16x32_f16(ql[1][ds], kbh, S[1][nt], 0, 0, 0);
      }
    }
#pragma unroll
    for (int mt = 0; mt < 2; ++mt)
#pragma unroll
      for (int nt = 0; nt < 4; ++nt)
#pragma unroll
        for (int r = 0; r < 4; ++r)
          Lacc[mt][r] += __builtin_amdgcn_exp2f(S[mt][nt][r] * LOG2E_SCALE);
    __builtin_amdgcn_s_barrier();
  }
  float invL[2][4];
  double dinvL[2][4];
#pragma unroll
  for (int mt = 0; mt < 2; ++mt)
#pragma unroll
    for (int r = 0; r < 4; ++r) {
      float x = Lacc[mt][r];
      x += __shfl_xor(x, 1); x += __shfl_xor(x, 2);
      x += __shfl_xor(x, 4); x += __shfl_xor(x, 8);
      invL[mt][r] = 1.0f / x;   // row = mt*16 + l4*4 + r (matches C-layout)
      dinvL[mt][r] = (double)invL[mt][r];
    }

  // ---- pass 2: p, cs (f64, wave-reduced atomics), PV ----
  // per-mt group index (a 32-row wave can span a BM=192 boundary; 16-row tiles cannot)
  double* csrow[2];
#pragma unroll
  for (int mt = 0; mt < 2; ++mt)
    csrow[mt] = csb + ((size_t)h * G + (rowbase + mt * 16) / BM) * NN;
  floatx4 O[2][8];
#pragma unroll
  for (int mt = 0; mt < 2; ++mt)
#pragma unroll
    for (int dt = 0; dt < 8; ++dt) O[mt][dt] = fzero4();

#pragma unroll 1
  for (int t = 0; t < 48; ++t) {
    const int kc = t * 64;
    STAGE_K(kc)
    WAITVM0();
    __builtin_amdgcn_s_barrier();
    floatx4 S[2][4];
#pragma unroll
    for (int mt = 0; mt < 2; ++mt)
#pragma unroll
      for (int nt = 0; nt < 4; ++nt) S[mt][nt] = fzero4();
#pragma unroll
    for (int nt = 0; nt < 4; ++nt) {
      const int rb = (nt * 16 + l15) * 128;
#pragma unroll
      for (int ds = 0; ds < 4; ++ds) {
        half8 kbh = *(const half8*)&skK[rb + kcol[ds]];
        half8 kbl = *(const half8*)&skK[8192 + rb + kcol[ds]];
        S[0][nt] = __builtin_amdgcn_mfma_f32_16x16x32_f16(qh[0][ds], kbh, S[0][nt], 0, 0, 0);
        S[1][nt] = __builtin_amdgcn_mfma_f32_16x16x32_f16(qh[1][ds], kbh, S[1][nt], 0, 0, 0);
        S[0][nt] = __builtin_amdgcn_mfma_f32_16x16x32_f16(qh[0][ds], kbl, S[0][nt], 0, 0, 0);
        S[1][nt] = __builtin_amdgcn_mfma_f32_16x16x32_f16(qh[1][ds], kbl, S[1][nt], 0, 0, 0);
        S[0][nt] = __builtin_amdgcn_mfma_f32_16x16x32_f16(ql[0][ds], kbh, S[0][nt], 0, 0, 0);
        S[1][nt] = __builtin_amdgcn_mfma_f32_16x16x32_f16(ql[1][ds], kbh, S[1][nt], 0, 0, 0);
      }
    }
    // batch V fragments (ks=0) early: L2 latency hides under the exp/cs VALU phase
    half8 vb[8];
#pragma unroll
    for (int dt = 0; dt < 8; ++dt)
      vb[dt] = *(const half8*)(vh + (size_t)(dt * 16 + l15) * NN + kc + l4 * 8);
    // exp, cs partial (f64), P stripes (per-wave private LDS; no barrier needed)
#pragma unroll
    for (int mt = 0; mt < 2; ++mt) {
      float* p_wave = &p_sh[wave][mt][0];
#pragma unroll
      for (int nt = 0; nt < 4; ++nt) {
        float e0 = __builtin_amdgcn_exp2f(S[mt][nt][0] * LOG2E_SCALE);
        float e1 = __builtin_amdgcn_exp2f(S[mt][nt][1] * LOG2E_SCALE);
        float e2 = __builtin_amdgcn_exp2f(S[mt][nt][2] * LOG2E_SCALE);
        float e3 = __builtin_amdgcn_exp2f(S[mt][nt][3] * LOG2E_SCALE);
        const int base = (l4 * 4) * PST + nt * 16 + l15;
        p_wave[base] = e0; p_wave[base + PST] = e1;
        p_wave[base + 2 * PST] = e2; p_wave[base + 3 * PST] = e3;
        double csp = (double)e0 * dinvL[mt][0] + (double)e1 * dinvL[mt][1]
                   + (double)e2 * dinvL[mt][2] + (double)e3 * dinvL[mt][3];
        csp += __shfl_xor(csp, 16);
        csp += __shfl_xor(csp, 32);
        if (lane < 16) atomicAdd(&csrow[mt][kc + nt * 16 + l15], csp);
      }
    }
    // PV ks=0: A = P stripe (per-wave LDS), B = vb (direct global), shared across mt
    {
      half8 pa[2];
#pragma unroll
      for (int mt = 0; mt < 2; ++mt) {
        const float* pp = &p_sh[wave][mt][0] + l15 * PST + l4 * 8;
        pa[mt] = pack_h8_rtz(*(const float4*)pp, *(const float4*)(pp + 4));
      }
#pragma unroll
      for (int dt = 0; dt < 8; ++dt) {
        O[0][dt] = __builtin_amdgcn_mfma_f32_16x16x32_f16(pa[0], vb[dt], O[0][dt], 0, 0, 0);
        O[1][dt] = __builtin_amdgcn_mfma_f32_16x16x32_f16(pa[1], vb[dt], O[1][dt], 0, 0, 0);
      }
    }
    // PV ks=1
#pragma unroll
    for (int dt = 0; dt < 8; ++dt)
      vb[dt] = *(const half8*)(vh + (size_t)(dt * 16 + l15) * NN + kc + 32 + l4 * 8);
    {
      half8 pa[2];
#pragma unroll
      for (int mt = 0; mt < 2; ++mt) {
        const float* pp = &p_sh[wave][mt][0] + l15 * PST + 32 + l4 * 8;
        pa[mt] = pack_h8_rtz(*(const float4*)pp, *(const float4*)(pp + 4));
      }
#pragma unroll
      for (int dt = 0; dt < 8; ++dt) {
        O[0][dt] = __builtin_amdgcn_mfma_f32_16x16x32_f16(pa[0], vb[dt], O[0][dt], 0, 0, 0);
        O[1][dt] = __builtin_amdgcn_mfma_f32_16x16x32_f16(pa[1], vb[dt], O[1][dt], 0, 0, 0);
      }
    }
    __builtin_amdgcn_s_barrier();
  }
#undef STAGE_K
  // epilogue: normalize rows, store o
#pragma unroll
  for (int mt = 0; mt < 2; ++mt)
#pragma unroll
    for (int dt = 0; dt < 8; ++dt)
#pragma unroll
      for (int r = 0; r < 4; ++r) {
        size_t idx = ((size_t)(h * NN + rowbase + mt * 16 + l4 * 4 + r)) * D + dt * 16 + l15;
        out[idx] = O[mt][dt][r] * invL[mt][r];
      }
}

// ---------------- exact top-k per (h,g) on f64 cs: mask |= top-896 ----------------
__global__ __launch_bounds__(256)
void topk_kernel(const double* __restrict__ csb, float* __restrict__ maskb) {
  const int hg = blockIdx.x;
  const double* cs = csb + (size_t)hg * NN;
  float* mask = maskb + (size_t)hg * NN;
  __shared__ unsigned long long vals[NN];  // 24 KB; cs > 0 so u64 order == double order
  __shared__ int wsum[4];
  const int tid = threadIdx.x;
  for (int i = tid; i < NN; i += 256)
    vals[i] = (unsigned long long)__double_as_longlong(cs[i]);
  __syncthreads();
  // greedy MSB search: largest T with count(v >= T) >= K  ->  T = K-th largest value
  unsigned long long T = 0ull;
  for (int b = 62; b >= 0; --b) {
    unsigned long long cand = T | (1ull << b);
    int c = 0;
    for (int i = tid; i < NN; i += 256) c += (vals[i] >= cand) ? 1 : 0;
#pragma unroll
    for (int off = 32; off; off >>= 1) c += __shfl_xor(c, off);
    if ((tid & 63) == 0) wsum[tid >> 6] = c;
    __syncthreads();
    int total = wsum[0] + wsum[1] + wsum[2] + wsum[3];
    if (total >= TOPK_K) T = cand;
    __syncthreads();
  }
  // lax.top_k tie-break: all (> T), then (== T) in increasing index order
  int c = 0;
  for (int i = tid; i < NN; i += 256) c += (vals[i] > T) ? 1 : 0;
#pragma unroll
  for (int off = 32; off; off >>= 1) c += __shfl_xor(c, off);
  if ((tid & 63) == 0) wsum[tid >> 6] = c;
  __syncthreads();
  int cgt = wsum[0] + wsum[1] + wsum[2] + wsum[3];
  int need = TOPK_K - cgt;
  for (int i = tid; i < NN; i += 256)
    if (vals[i] > T) mask[i] = 1.0f;
  __syncthreads();
  if (tid == 0) {
    int c2 = 0;
    for (int i = 0; i < NN && c2 < need; ++i)
      if (vals[i] == T) { mask[i] = 1.0f; ++c2; }
  }
}

// ---------------- sparse attention: same structure, single pass, plain f16 ----------------
__global__ __launch_bounds__(256, 3)
void sparse_kernel(const float* __restrict__ q, const _Float16* __restrict__ kf,
                   const _Float16* __restrict__ vT, const float* __restrict__ maskb,
                   float* __restrict__ out) {
  __shared__ __align__(16) _Float16 skK[8192];            // 16 KB
  __shared__ __align__(16) float p_sh[4][2][16 * PST];    // 34.8 KB
  const int tid = threadIdx.x;
  const int wave = tid >> 6, lane = tid & 63;
  const int l15 = lane & 15, l4 = lane >> 4;
  const int wq = ((blockIdx.x & 7) * 72) + (blockIdx.x >> 3);
  const int h = wq / 24;
  const int m0 = (wq % 24) * 128;
  const int rowbase = m0 + wave * 32;
  const _Float16* kh = kf + (size_t)h * NN * D;
  const _Float16* vh = vT + (size_t)h * D * NN;

#define SSTAGE(kc_) {                                                           \
  _Pragma("unroll") for (int i_ = 0; i_ < 4; ++i_) {                            \
    int c_ = wave * 4 + i_;                                                     \
    int row_ = c_ * 4 + l4;                                                     \
    int gc_ = l15 ^ (4 * (i_ & 1) + l4);                                        \
    GLOAD_LDS(kh + (size_t)((kc_) + row_) * D + gc_ * 8, &skK[c_ * 512]);       \
  } }

  int kcol[4];
#pragma unroll
  for (int ds = 0; ds < 4; ++ds) kcol[ds] = ((ds * 4 + l4) ^ (l15 & 7)) * 8;

  half8 qa[2][4];
#pragma unroll
  for (int mt = 0; mt < 2; ++mt)
#pragma unroll
    for (int ds = 0; ds < 4; ++ds) {
      const float* qp = q + ((size_t)(h * NN + rowbase + mt * 16 + l15)) * D + ds * 32 + l4 * 8;
      qa[mt][ds] = pack_h8_rte(*(const float4*)qp, *(const float4*)(qp + 4));
    }

  const float* mrow[2];
#pragma unroll
  for (int mt = 0; mt < 2; ++mt)
    mrow[mt] = maskb + ((size_t)h * G + (rowbase + mt * 16) / BM) * NN;

  float lacc[2][4] = {{0.f, 0.f, 0.f, 0.f}, {0.f, 0.f, 0.f, 0.f}};
  floatx4 O[2][8];
#pragma unroll
  for (int mt = 0; mt < 2; ++mt)
#pragma unroll
    for (int dt = 0; dt < 8; ++dt) O[mt][dt] = fzero4();

#pragma unroll 1
  for (int t = 0; t < 48; ++t) {
    const int kc = t * 64;
    SSTAGE(kc)
    WAITVM0();
    __builtin_amdgcn_s_barrier();
    float mv[2][4];
#pragma unroll
    for (int mt = 0; mt < 2; ++mt)
#pragma unroll
      for (int nt = 0; nt < 4; ++nt) mv[mt][nt] = mrow[mt][kc + nt * 16 + l15];
    floatx4 S[2][4];
#pragma unroll
    for (int mt = 0; mt < 2; ++mt)
#pragma unroll
      for (int nt = 0; nt < 4; ++nt) S[mt][nt] = fzero4();
#pragma unroll
    for (int nt = 0; nt < 4; ++nt) {
      const int rb = (nt * 16 + l15) * 128;
#pragma unroll
      for (int ds = 0; ds < 4; ++ds) {
        half8 kb = *(const half8*)&skK[rb + kcol[ds]];
        S[0][nt] = __builtin_amdgcn_mfma_f32_16x16x32_f16(qa[0][ds], kb, S[0][nt], 0, 0, 0);
        S[1][nt] = __builtin_amdgcn_mfma_f32_16x16x32_f16(qa[1][ds], kb, S[1][nt], 0, 0, 0);
      }
    }
    half8 vb[8];
#pragma unroll
    for (int dt = 0; dt < 8; ++dt)
      vb[dt] = *(const half8*)(vh + (size_t)(dt * 16 + l15) * NN + kc + l4 * 8);
#pragma unroll
    for (int mt = 0; mt < 2; ++mt) {
      float* p_wave = &p_sh[wave][mt][0];
#pragma unroll
      for (int nt = 0; nt < 4; ++nt) {
        float e0 = __builtin_amdgcn_exp2f(S[mt][nt][0] * LOG2E_SCALE) * mv[mt][nt];
        float e1 = __builtin_amdgcn_exp2f(S[mt][nt][1] * LOG2E_SCALE) * mv[mt][nt];
        float e2 = __builtin_amdgcn_exp2f(S[mt][nt][2] * LOG2E_SCALE) * mv[mt][nt];
        float e3 = __builtin_amdgcn_exp2f(S[mt][nt][3] * LOG2E_SCALE) * mv[mt][nt];
        lacc[mt][0] += e0; lacc[mt][1] += e1; lacc[mt][2] += e2; lacc[mt][3] += e3;
        const int base = (l4 * 4) * PST + nt * 16 + l15;
        p_wave[base] = e0; p_wave[base + PST] = e1;
        p_wave[base + 2 * PST] = e2; p_wave[base + 3 * PST] = e3;
      }
    }
    {
      half8 pa[2];
#pragma unroll
      for (int mt = 0; mt < 2; ++mt) {
        const float* pp = &p_sh[wave][mt][0] + l15 * PST + l4 * 8;
        pa[mt] = pack_h8_rtz(*(const float4*)pp, *(const float4*)(pp + 4));
      }
#pragma unroll
      for (int dt = 0; dt < 8; ++dt) {
        O[0][dt] = __builtin_amdgcn_mfma_f32_16x16x32_f16(pa[0], vb[dt], O[0][dt], 0, 0, 0);
        O[1][dt] = __builtin_amdgcn_mfma_f32_16x16x32_f16(pa[1], vb[dt], O[1][dt], 0, 0, 0);
      }
    }
#pragma unroll
    for (int dt = 0; dt < 8; ++dt)
      vb[dt] = *(const half8*)(vh + (size_t)(dt * 16 + l15) * NN + kc + 32 + l4 * 8);
    {
      half8 pa[2];
#pragma unroll
      for (int mt = 0; mt < 2; ++mt) {
        const float* pp = &p_sh[wave][mt][0] + l15 * PST + 32 + l4 * 8;
        pa[mt] = pack_h8_rtz(*(const float4*)pp, *(const float4*)(pp + 4));
      }
#pragma unroll
      for (int dt = 0; dt < 8; ++dt) {
        O[0][dt] = __builtin_amdgcn_mfma_f32_16x16x32_f16(pa[0], vb[dt], O[0][dt], 0, 0, 0);
        O[1][dt] = __builtin_amdgcn_mfma_f32_16x16x32_f16(pa[1], vb[dt], O[1][dt], 0, 0, 0);
      }
    }
    __builtin_amdgcn_s_barrier();
  }
#undef SSTAGE
  float invl[2][4];
#pragma unroll
  for (int mt = 0; mt < 2; ++mt)
#pragma unroll
    for (int r = 0; r < 4; ++r) {
      float x = lacc[mt][r];
      x += __shfl_xor(x, 1); x += __shfl_xor(x, 2);
      x += __shfl_xor(x, 4); x += __shfl_xor(x, 8);
      invl[mt][r] = 1.0f / x;
    }
#pragma unroll
  for (int mt = 0; mt < 2; ++mt)
#pragma unroll
    for (int dt = 0; dt < 8; ++dt)
#pragma unroll
      for (int r = 0; r < 4; ++r) {
        size_t idx = ((size_t)(h * NN + rowbase + mt * 16 + l4 * 4 + r)) * D + dt * 16 + l15;
        out[OUT2_OFF + idx] = out[idx] - O[mt][dt][r] * invl[mt][r];
      }
}

// ---------------- launch ----------------
extern "C" void kernel_launch(void* const* d_in, const int* in_sizes, int n_in,
                              void* d_out, int out_size, void* d_ws, size_t ws_size,
                              hipStream_t stream) {
  const float* q = (const float*)d_in[0];
  const float* k = (const float*)d_in[1];
  const float* v = (const float*)d_in[2];
  float* out = (float*)d_out;
  char* wsb = (char*)d_ws;

  // ws layout: khi | klo | vT | cs(double) | mask   (~71 MB total)
  _Float16* khi = (_Float16*)wsb;
  _Float16* klo = (_Float16*)(wsb + KV_HALF_BYTES);
  _Float16* vT  = (_Float16*)(wsb + 2 * KV_HALF_BYTES);
  double* csb   = (double*)(wsb + 3 * KV_HALF_BYTES);
  float* maskb  = (float*)(wsb + 3 * KV_HALF_BYTES + CSD_BYTES);

  (void)hipMemsetAsync(csb, 0, CSD_BYTES, stream);
  cvt_k_kernel<<<dim3((H * NN * D) / (8 * 256)), dim3(256), 0, stream>>>(k, khi, klo);
  cvt_vT_kernel<<<dim3(NN / 64, D / 64, H), dim3(256), 0, stream>>>(v, vT);
  rmask_kernel<<<dim3(H * G * NN / 256), dim3(256), 0, stream>>>(maskb);
  dense_kernel<<<dim3((NN / 128) * H), dim3(256), 0, stream>>>(q, khi, klo, vT, out, csb);
  topk_kernel<<<dim3(H * G), dim3(256), 0, stream>>>(csb, maskb);
  sparse_kernel<<<dim3((NN / 128) * H), dim3(256), 0, stream>>>(q, khi, vT, maskb, out);
}

// Round 5
// 1360.015 us; speedup vs baseline: 1.2315x; 1.2315x over previous
//
#include <hip/hip_runtime.h>
#include <math.h>

// Problem constants (b=1 hard-coded)
#define H  24
#define NN 3072
#define D  128
#define G  16
#define BM 192
#define TOPK_K 896
#define PST 34             // P-tile LDS row stride (floats); 34%32=2 -> 2-way (free) r/w
#define OUT2_OFF ((size_t)H * NN * D)
#define KV_HALF_BYTES ((size_t)H * NN * D * 2)   // 18874368
#define CSD_BYTES ((size_t)H * G * NN * 8)       // 9437184 (float64 cs)

// exp(s*scale) = exp2(s * scale * log2(e)); scale = 1/sqrt(128)
#define LOG2E_SCALE 0.12751743822f

typedef _Float16 half8 __attribute__((ext_vector_type(8)));
typedef _Float16 half4v __attribute__((ext_vector_type(4)));
typedef __fp16 fp16x2 __attribute__((ext_vector_type(2)));
typedef float floatx4 __attribute__((ext_vector_type(4)));

// async global->LDS, 16B per lane; LDS dest = wave-uniform base + lane*16 (HW rule)
#define GLOAD_LDS(g, l) __builtin_amdgcn_global_load_lds( \
    (const __attribute__((address_space(1))) void*)(g),   \
    (__attribute__((address_space(3))) void*)(l), 16, 0, 0)
#define WAITVM(N) asm volatile("s_waitcnt vmcnt(" #N ")" ::: "memory")

__device__ __forceinline__ floatx4 fzero4() {
  floatx4 z = {0.f, 0.f, 0.f, 0.f};
  return z;
}
// RTE pack (unbiased) — used for input fragments
__device__ __forceinline__ half8 pack_h8_rte(float4 a, float4 b) {
  half8 r;
  r[0] = (_Float16)a.x; r[1] = (_Float16)a.y; r[2] = (_Float16)a.z; r[3] = (_Float16)a.w;
  r[4] = (_Float16)b.x; r[5] = (_Float16)b.y; r[6] = (_Float16)b.z; r[7] = (_Float16)b.w;
  return r;
}
// RTZ packed cvt (1 instr per pair) — used for P (p>=0; small bias cancels in o - sp)
__device__ __forceinline__ half8 pack_h8_rtz(float4 a, float4 b) {
  fp16x2 h0 = __builtin_amdgcn_cvt_pkrtz(a.x, a.y);
  fp16x2 h1 = __builtin_amdgcn_cvt_pkrtz(a.z, a.w);
  fp16x2 h2 = __builtin_amdgcn_cvt_pkrtz(b.x, b.y);
  fp16x2 h3 = __builtin_amdgcn_cvt_pkrtz(b.z, b.w);
  half8 r;
  r[0] = (_Float16)h0[0]; r[1] = (_Float16)h0[1];
  r[2] = (_Float16)h1[0]; r[3] = (_Float16)h1[1];
  r[4] = (_Float16)h2[0]; r[5] = (_Float16)h2[1];
  r[6] = (_Float16)h3[0]; r[7] = (_Float16)h3[1];
  return r;
}
// residual: x - (float)f16(x)
__device__ __forceinline__ half8 pack_h8_residual(float4 a, float4 b, half8 hi) {
  float4 ra = make_float4(a.x - (float)hi[0], a.y - (float)hi[1],
                          a.z - (float)hi[2], a.w - (float)hi[3]);
  float4 rb = make_float4(b.x - (float)hi[4], b.y - (float)hi[5],
                          b.z - (float)hi[6], b.w - (float)hi[7]);
  return pack_h8_rte(ra, rb);
}

// ---------------- threefry2x32 (exact JAX semantics, validated round 1) ----------------
__device__ __forceinline__ void tf2x32(unsigned k0, unsigned k1, unsigned x0, unsigned x1,
                                       unsigned* o0, unsigned* o1) {
  unsigned ks2 = k0 ^ k1 ^ 0x1BD11BDAu;
  unsigned v0 = x0 + k0, v1 = x1 + k1;
#define TF_RND(r) { v0 += v1; v1 = (v1 << (r)) | (v1 >> (32 - (r))); v1 ^= v0; }
  TF_RND(13) TF_RND(15) TF_RND(26) TF_RND(6)   v0 += k1;  v1 += ks2 + 1u;
  TF_RND(17) TF_RND(29) TF_RND(16) TF_RND(24)  v0 += ks2; v1 += k0 + 2u;
  TF_RND(13) TF_RND(15) TF_RND(26) TF_RND(6)   v0 += k0;  v1 += k1 + 3u;
  TF_RND(17) TF_RND(29) TF_RND(16) TF_RND(24)  v0 += k1;  v1 += ks2 + 4u;
  TF_RND(13) TF_RND(15) TF_RND(26) TF_RND(6)   v0 += ks2; v1 += k0 + 5u;
#undef TF_RND
  *o0 = v0; *o1 = v1;
}

__global__ __launch_bounds__(256)
void rmask_kernel(float* __restrict__ mask) {
  const unsigned S = H * G * NN;
  unsigned i = blockIdx.x * 256u + threadIdx.x;
  if (i >= S) return;
  unsigned hb, lb, a, b;
  unsigned k1a, k1b, k2a, k2b;
  tf2x32(0u, 1u, 0u, 0u, &k1a, &k1b);
  tf2x32(0u, 1u, 0u, 1u, &k2a, &k2b);
  tf2x32(k1a, k1b, 0u, i, &a, &b); hb = a ^ b;
  tf2x32(k2a, k2b, 0u, i, &a, &b); lb = a ^ b;
  unsigned r = ((hb % 100u) * 96u + (lb % 100u)) % 100u;
  mask[i] = (r == 0u) ? 1.0f : 0.0f;
}

// ---------------- phase 0: k -> f16 hi + f16 residual (row-major) ----------------
__global__ __launch_bounds__(256)
void cvt_k_kernel(const float* __restrict__ k, _Float16* __restrict__ khi,
                  _Float16* __restrict__ klo) {
  size_t i = (size_t)blockIdx.x * 256 + threadIdx.x;   // 8 elems per thread
  const float4* src = (const float4*)k + i * 2;
  float4 a = src[0], b = src[1];
  half8 hi = pack_h8_rte(a, b);
  *(half8*)(khi + i * 8) = hi;
  *(half8*)(klo + i * 8) = pack_h8_residual(a, b, hi);
}

// ---------------- phase 0: v -> f16 transposed vT[h][d][key] ----------------
__global__ __launch_bounds__(256)
void cvt_vT_kernel(const float* __restrict__ v, _Float16* __restrict__ vT) {
  __shared__ _Float16 t[64][68];
  const int h = blockIdx.z, k0 = blockIdx.x * 64, d0 = blockIdx.y * 64;
  const int tid = threadIdx.x;
  const int c4 = tid & 15, r = tid >> 4;
#pragma unroll
  for (int i = 0; i < 4; ++i) {
    int row = r + i * 16;  // key row within tile
    float4 x = *(const float4*)(v + ((size_t)(h * NN + k0 + row)) * D + d0 + c4 * 4);
    t[c4 * 4 + 0][row] = (_Float16)x.x;
    t[c4 * 4 + 1][row] = (_Float16)x.y;
    t[c4 * 4 + 2][row] = (_Float16)x.z;
    t[c4 * 4 + 3][row] = (_Float16)x.w;
  }
  __syncthreads();
#pragma unroll
  for (int i = 0; i < 4; ++i) {
    int drow = r + i * 16;  // d within tile
    half4v val = *(const half4v*)&t[drow][c4 * 4];
    *(half4v*)(vT + (size_t)(h * D + d0 + drow) * NN + k0 + c4 * 4) = val;
  }
}

// ---------------- dense attention: R=32/wave, TK=32 double-buffered K LDS, V direct ----------------
// 4 waves x 32 query rows = 128 rows/block, grid 576; LDS = K dbuf 32 KB + P 17 KB = 50 KB
// -> 2 blocks/CU. Counted vmcnt(4): stage(t+1) stays in flight across the barrier (never
// drain to 0 in-loop; round-3's vmcnt(0) serialization was the regression).
// K-fragment b128 reads feed 6 MFMAs (2 mt x 3 split terms). V direct from L2-resident vT
// (parallel VMEM pipe). Source-swizzled staging keeps K reads bank-conflict-minimal.
// Round-5 fix: pass-2 split term was ql*kbl (typo) -> ql*kbh, matching pass 1.
__global__ __launch_bounds__(256, 2)
void dense_kernel(const float* __restrict__ q, const _Float16* __restrict__ khi_g,
                  const _Float16* __restrict__ klo_g, const _Float16* __restrict__ vT,
                  float* __restrict__ out, double* __restrict__ csb) {
  __shared__ __align__(16) _Float16 skK[2][8192];         // per buf: khi 32x128 | klo 32x128
  __shared__ __align__(16) float p_sh[4][2][16 * PST];    // per-wave per-mt stripes, 17 KB
  const int tid = threadIdx.x;
  const int wave = tid >> 6, lane = tid & 63;
  const int l15 = lane & 15, l4 = lane >> 4;
  // XCD swizzle: 576 = 8 * 72, bijective
  const int wq = ((blockIdx.x & 7) * 72) + (blockIdx.x >> 3);
  const int h = wq / 24;
  const int m0 = (wq % 24) * 128;
  const int rowbase = m0 + wave * 32;
  const _Float16* khi = khi_g + (size_t)h * NN * D;
  const _Float16* klo = klo_g + (size_t)h * NN * D;
  const _Float16* vh = vT + (size_t)h * D * NN;

  // staging: 16 chunks of 1 KB (0-7 khi rows 4c.., 8-15 klo). wave w: chunks w*4+i.
  // source col16 pre-swizzled gc = l15 ^ (row & 7); LDS linear (gload_lds rule).
  const _Float16* ksrc = (wave < 2) ? khi : klo;
#define STAGE_K(kc_, buf_) {                                                    \
  _Pragma("unroll") for (int i_ = 0; i_ < 4; ++i_) {                            \
    int c_ = wave * 4 + i_;                                                     \
    int row_ = (c_ & 7) * 4 + l4;                                               \
    int gc_ = l15 ^ ((c_ & 1) * 4 + l4);                                        \
    GLOAD_LDS(ksrc + (size_t)((kc_) + row_) * D + gc_ * 8, &skK[buf_][c_ * 512]); \
  } }

  // fragment read columns (same XOR as staged source)
  int kcol[4];
#pragma unroll
  for (int ds = 0; ds < 4; ++ds) kcol[ds] = ((ds * 4 + l4) ^ (l15 & 7)) * 8;

  // Q A-fragments hi+lo for 2 row tiles: A[m = mt*16 + l15][k = l4*8+j]
  half8 qh[2][4], ql[2][4];
#pragma unroll
  for (int mt = 0; mt < 2; ++mt)
#pragma unroll
    for (int ds = 0; ds < 4; ++ds) {
      const float* qp = q + ((size_t)(h * NN + rowbase + mt * 16 + l15)) * D + ds * 32 + l4 * 8;
      float4 a = *(const float4*)qp, b = *(const float4*)(qp + 4);
      qh[mt][ds] = pack_h8_rte(a, b);
      ql[mt][ds] = pack_h8_residual(a, b, qh[mt][ds]);
    }

  // ---- pass 1: row sums L (split-precision QK^T) ----
  float Lacc[2][4] = {{0.f, 0.f, 0.f, 0.f}, {0.f, 0.f, 0.f, 0.f}};
  STAGE_K(0, 0)
#pragma unroll 1
  for (int t = 0; t < 96; ++t) {
    const int tn = ((t + 1) % 96) * 32;      // t=95 wraps: pre-stages pass-2 tile 0 in buf0
    STAGE_K(tn, (t + 1) & 1)
    WAITVM(4);
    __builtin_amdgcn_s_barrier();
    const _Float16* bk = &skK[t & 1][0];
    floatx4 S[2][2];
#pragma unroll
    for (int mt = 0; mt < 2; ++mt)
#pragma unroll
      for (int nt = 0; nt < 2; ++nt) S[mt][nt] = fzero4();
#pragma unroll
    for (int nt = 0; nt < 2; ++nt) {
      const int rb = (nt * 16 + l15) * 128;
#pragma unroll
      for (int ds = 0; ds < 4; ++ds) {
        half8 kbh = *(const half8*)&bk[rb + kcol[ds]];
        half8 kbl = *(const half8*)&bk[4096 + rb + kcol[ds]];
        S[0][nt] = __builtin_amdgcn_mfma_f32_16x16x32_f16(qh[0][ds], kbh, S[0][nt], 0, 0, 0);
        S[1][nt] = __builtin_amdgcn_mfma_f32_16x16x32_f16(qh[1][ds], kbh, S[1][nt], 0, 0, 0);
        S[0][nt] = __builtin_amdgcn_mfma_f32_16x16x32_f16(qh[0][ds], kbl, S[0][nt], 0, 0, 0);
        S[1][nt] = __builtin_amdgcn_mfma_f32_16x16x32_f16(qh[1][ds], kbl, S[1][nt], 0, 0, 0);
        S[0][nt] = __builtin_amdgcn_mfma_f32_16x16x32_f16(ql[0][ds], kbh, S[0][nt], 0, 0, 0);
        S[1][nt] = __builtin_amdgcn_mfma_f32_16x16x32_f16(ql[1][ds], kbh, S[1][nt], 0, 0, 0);
      }
    }
#pragma unroll
    for (int mt = 0; mt < 2; ++mt)
#pragma unroll
      for (int nt = 0; nt < 2; ++nt)
#pragma unroll
        for (int r = 0; r < 4; ++r)
          Lacc[mt][r] += __builtin_amdgcn_exp2f(S[mt][nt][r] * LOG2E_SCALE);
    __builtin_amdgcn_s_barrier();
  }
  float invL[2][4];
  double dinvL[2][4];
#pragma unroll
  for (int mt = 0; mt < 2; ++mt)
#pragma unroll
    for (int r = 0; r < 4; ++r) {
      float x = Lacc[mt][r];
      x += __shfl_xor(x, 1); x += __shfl_xor(x, 2);
      x += __shfl_xor(x, 4); x += __shfl_xor(x, 8);
      invL[mt][r] = 1.0f / x;   // row = mt*16 + l4*4 + r (matches C-layout)
      dinvL[mt][r] = (double)invL[mt][r];
    }

  // ---- pass 2: p, cs (f64, wave-reduced atomics), PV ----
  // Tile 0 already staged in buf0 by pass 1's wrap stage; parities line up (t&1).
  double* csrow[2];
#pragma unroll
  for (int mt = 0; mt < 2; ++mt)
    csrow[mt] = csb + ((size_t)h * G + (rowbase + mt * 16) / BM) * NN;
  floatx4 O[2][8];
#pragma unroll
  for (int mt = 0; mt < 2; ++mt)
#pragma unroll
    for (int dt = 0; dt < 8; ++dt) O[mt][dt] = fzero4();

#pragma unroll 1
  for (int t = 0; t < 96; ++t) {
    const int kc = t * 32;
    const int tn = ((t + 1) % 96) * 32;
    STAGE_K(tn, (t + 1) & 1)
    WAITVM(4);
    __builtin_amdgcn_s_barrier();
    const _Float16* bk = &skK[t & 1][0];
    floatx4 S[2][2];
#pragma unroll
    for (int mt = 0; mt < 2; ++mt)
#pragma unroll
      for (int nt = 0; nt < 2; ++nt) S[mt][nt] = fzero4();
#pragma unroll
    for (int nt = 0; nt < 2; ++nt) {
      const int rb = (nt * 16 + l15) * 128;
#pragma unroll
      for (int ds = 0; ds < 4; ++ds) {
        half8 kbh = *(const half8*)&bk[rb + kcol[ds]];
        half8 kbl = *(const half8*)&bk[4096 + rb + kcol[ds]];
        S[0][nt] = __builtin_amdgcn_mfma_f32_16x16x32_f16(qh[0][ds], kbh, S[0][nt], 0, 0, 0);
        S[1][nt] = __builtin_amdgcn_mfma_f32_16x16x32_f16(qh[1][ds], kbh, S[1][nt], 0, 0, 0);
        S[0][nt] = __builtin_amdgcn_mfma_f32_16x16x32_f16(qh[0][ds], kbl, S[0][nt], 0, 0, 0);
        S[1][nt] = __builtin_amdgcn_mfma_f32_16x16x32_f16(qh[1][ds], kbl, S[1][nt], 0, 0, 0);
        S[0][nt] = __builtin_amdgcn_mfma_f32_16x16x32_f16(ql[0][ds], kbh, S[0][nt], 0, 0, 0);
        S[1][nt] = __builtin_amdgcn_mfma_f32_16x16x32_f16(ql[1][ds], kbh, S[1][nt], 0, 0, 0);
      }
    }
    // batch V fragments early: L2 latency hides under the exp/cs VALU phase
    half8 vb[8];
#pragma unroll
    for (int dt = 0; dt < 8; ++dt)
      vb[dt] = *(const half8*)(vh + (size_t)(dt * 16 + l15) * NN + kc + l4 * 8);
    // exp, cs partial (f64), P stripes (per-wave private LDS; no barrier needed)
#pragma unroll
    for (int mt = 0; mt < 2; ++mt) {
      float* p_wave = &p_sh[wave][mt][0];
#pragma unroll
      for (int nt = 0; nt < 2; ++nt) {
        float e0 = __builtin_amdgcn_exp2f(S[mt][nt][0] * LOG2E_SCALE);
        float e1 = __builtin_amdgcn_exp2f(S[mt][nt][1] * LOG2E_SCALE);
        float e2 = __builtin_amdgcn_exp2f(S[mt][nt][2] * LOG2E_SCALE);
        float e3 = __builtin_amdgcn_exp2f(S[mt][nt][3] * LOG2E_SCALE);
        const int base = (l4 * 4) * PST + nt * 16 + l15;
        p_wave[base] = e0; p_wave[base + PST] = e1;
        p_wave[base + 2 * PST] = e2; p_wave[base + 3 * PST] = e3;
        double csp = (double)e0 * dinvL[mt][0] + (double)e1 * dinvL[mt][1]
                   + (double)e2 * dinvL[mt][2] + (double)e3 * dinvL[mt][3];
        csp += __shfl_xor(csp, 16);
        csp += __shfl_xor(csp, 32);
        if (lane < 16) atomicAdd(&csrow[mt][kc + nt * 16 + l15], csp);
      }
    }
    // PV: A = P stripe (per-wave LDS), B = vb (direct global), shared across mt
    {
      half8 pa[2];
#pragma unroll
      for (int mt = 0; mt < 2; ++mt) {
        const float* pp = &p_sh[wave][mt][0] + l15 * PST + l4 * 8;
        pa[mt] = pack_h8_rtz(*(const float4*)pp, *(const float4*)(pp + 4));
      }
#pragma unroll
      for (int dt = 0; dt < 8; ++dt) {
        O[0][dt] = __builtin_amdgcn_mfma_f32_16x16x32_f16(pa[0], vb[dt], O[0][dt], 0, 0, 0);
        O[1][dt] = __builtin_amdgcn_mfma_f32_16x16x32_f16(pa[1], vb[dt], O[1][dt], 0, 0, 0);
      }
    }
    __builtin_amdgcn_s_barrier();
  }
#undef STAGE_K
  WAITVM(0);   // drain dummy wrap stage before LDS dealloc (block retire)
  // epilogue: normalize rows, store o
#pragma unroll
  for (int mt = 0; mt < 2; ++mt)
#pragma unroll
    for (int dt = 0; dt < 8; ++dt)
#pragma unroll
      for (int r = 0; r < 4; ++r) {
        size_t idx = ((size_t)(h * NN + rowbase + mt * 16 + l4 * 4 + r)) * D + dt * 16 + l15;
        out[idx] = O[mt][dt][r] * invL[mt][r];
      }
}

// ---------------- exact top-k per (h,g) on f64 cs: mask |= top-896 ----------------
__global__ __launch_bounds__(256)
void topk_kernel(const double* __restrict__ csb, float* __restrict__ maskb) {
  const int hg = blockIdx.x;
  const double* cs = csb + (size_t)hg * NN;
  float* mask = maskb + (size_t)hg * NN;
  __shared__ unsigned long long vals[NN];  // 24 KB; cs > 0 so u64 order == double order
  __shared__ int wsum[4];
  const int tid = threadIdx.x;
  for (int i = tid; i < NN; i += 256)
    vals[i] = (unsigned long long)__double_as_longlong(cs[i]);
  __syncthreads();
  // greedy MSB search: largest T with count(v >= T) >= K  ->  T = K-th largest value
  unsigned long long T = 0ull;
  for (int b = 62; b >= 0; --b) {
    unsigned long long cand = T | (1ull << b);
    int c = 0;
    for (int i = tid; i < NN; i += 256) c += (vals[i] >= cand) ? 1 : 0;
#pragma unroll
    for (int off = 32; off; off >>= 1) c += __shfl_xor(c, off);
    if ((tid & 63) == 0) wsum[tid >> 6] = c;
    __syncthreads();
    int total = wsum[0] + wsum[1] + wsum[2] + wsum[3];
    if (total >= TOPK_K) T = cand;
    __syncthreads();
  }
  // lax.top_k tie-break: all (> T), then (== T) in increasing index order
  int c = 0;
  for (int i = tid; i < NN; i += 256) c += (vals[i] > T) ? 1 : 0;
#pragma unroll
  for (int off = 32; off; off >>= 1) c += __shfl_xor(c, off);
  if ((tid & 63) == 0) wsum[tid >> 6] = c;
  __syncthreads();
  int cgt = wsum[0] + wsum[1] + wsum[2] + wsum[3];
  int need = TOPK_K - cgt;
  for (int i = tid; i < NN; i += 256)
    if (vals[i] > T) mask[i] = 1.0f;
  __syncthreads();
  if (tid == 0) {
    int c2 = 0;
    for (int i = 0; i < NN && c2 < need; ++i)
      if (vals[i] == T) { mask[i] = 1.0f; ++c2; }
  }
}

// ---------------- sparse attention: same pipeline, single pass, plain f16 ----------------
__global__ __launch_bounds__(256, 3)
void sparse_kernel(const float* __restrict__ q, const _Float16* __restrict__ kf,
                   const _Float16* __restrict__ vT, const float* __restrict__ maskb,
                   float* __restrict__ out) {
  __shared__ __align__(16) _Float16 skK[2][4096];         // 8 KB per buffer
  __shared__ __align__(16) float p_sh[4][2][16 * PST];    // 17 KB
  const int tid = threadIdx.x;
  const int wave = tid >> 6, lane = tid & 63;
  const int l15 = lane & 15, l4 = lane >> 4;
  const int wq = ((blockIdx.x & 7) * 72) + (blockIdx.x >> 3);
  const int h = wq / 24;
  const int m0 = (wq % 24) * 128;
  const int rowbase = m0 + wave * 32;
  const _Float16* kh = kf + (size_t)h * NN * D;
  const _Float16* vh = vT + (size_t)h * D * NN;

#define SSTAGE(kc_, buf_) {                                                     \
  _Pragma("unroll") for (int i_ = 0; i_ < 2; ++i_) {                            \
    int c_ = wave * 2 + i_;                                                     \
    int row_ = c_ * 4 + l4;                                                     \
    int gc_ = l15 ^ ((c_ & 1) * 4 + l4);                                        \
    GLOAD_LDS(kh + (size_t)((kc_) + row_) * D + gc_ * 8, &skK[buf_][c_ * 512]); \
  } }

  int kcol[4];
#pragma unroll
  for (int ds = 0; ds < 4; ++ds) kcol[ds] = ((ds * 4 + l4) ^ (l15 & 7)) * 8;

  half8 qa[2][4];
#pragma unroll
  for (int mt = 0; mt < 2; ++mt)
#pragma unroll
    for (int ds = 0; ds < 4; ++ds) {
      const float* qp = q + ((size_t)(h * NN + rowbase + mt * 16 + l15)) * D + ds * 32 + l4 * 8;
      qa[mt][ds] = pack_h8_rte(*(const float4*)qp, *(const float4*)(qp + 4));
    }

  const float* mrow[2];
#pragma unroll
  for (int mt = 0; mt < 2; ++mt)
    mrow[mt] = maskb + ((size_t)h * G + (rowbase + mt * 16) / BM) * NN;

  float lacc[2][4] = {{0.f, 0.f, 0.f, 0.f}, {0.f, 0.f, 0.f, 0.f}};
  floatx4 O[2][8];
#pragma unroll
  for (int mt = 0; mt < 2; ++mt)
#pragma unroll
    for (int dt = 0; dt < 8; ++dt) O[mt][dt] = fzero4();

  SSTAGE(0, 0)
#pragma unroll 1
  for (int t = 0; t < 96; ++t) {
    const int kc = t * 32;
    const int tn = ((t + 1) % 96) * 32;
    SSTAGE(tn, (t + 1) & 1)
    WAITVM(2);
    __builtin_amdgcn_s_barrier();
    const _Float16* bk = &skK[t & 1][0];
    float mv[2][2];
#pragma unroll
    for (int mt = 0; mt < 2; ++mt)
#pragma unroll
      for (int nt = 0; nt < 2; ++nt) mv[mt][nt] = mrow[mt][kc + nt * 16 + l15];
    floatx4 S[2][2];
#pragma unroll
    for (int mt = 0; mt < 2; ++mt)
#pragma unroll
      for (int nt = 0; nt < 2; ++nt) S[mt][nt] = fzero4();
#pragma unroll
    for (int nt = 0; nt < 2; ++nt) {
      const int rb = (nt * 16 + l15) * 128;
#pragma unroll
      for (int ds = 0; ds < 4; ++ds) {
        half8 kb = *(const half8*)&bk[rb + kcol[ds]];
        S[0][nt] = __builtin_amdgcn_mfma_f32_16x16x32_f16(qa[0][ds], kb, S[0][nt], 0, 0, 0);
        S[1][nt] = __builtin_amdgcn_mfma_f32_16x16x32_f16(qa[1][ds], kb, S[1][nt], 0, 0, 0);
      }
    }
    half8 vb[8];
#pragma unroll
    for (int dt = 0; dt < 8; ++dt)
      vb[dt] = *(const half8*)(vh + (size_t)(dt * 16 + l15) * NN + kc + l4 * 8);
#pragma unroll
    for (int mt = 0; mt < 2; ++mt) {
      float* p_wave = &p_sh[wave][mt][0];
#pragma unroll
      for (int nt = 0; nt < 2; ++nt) {
        float e0 = __builtin_amdgcn_exp2f(S[mt][nt][0] * LOG2E_SCALE) * mv[mt][nt];
        float e1 = __builtin_amdgcn_exp2f(S[mt][nt][1] * LOG2E_SCALE) * mv[mt][nt];
        float e2 = __builtin_amdgcn_exp2f(S[mt][nt][2] * LOG2E_SCALE) * mv[mt][nt];
        float e3 = __builtin_amdgcn_exp2f(S[mt][nt][3] * LOG2E_SCALE) * mv[mt][nt];
        lacc[mt][0] += e0; lacc[mt][1] += e1; lacc[mt][2] += e2; lacc[mt][3] += e3;
        const int base = (l4 * 4) * PST + nt * 16 + l15;
        p_wave[base] = e0; p_wave[base + PST] = e1;
        p_wave[base + 2 * PST] = e2; p_wave[base + 3 * PST] = e3;
      }
    }
    {
      half8 pa[2];
#pragma unroll
      for (int mt = 0; mt < 2; ++mt) {
        const float* pp = &p_sh[wave][mt][0] + l15 * PST + l4 * 8;
        pa[mt] = pack_h8_rtz(*(const float4*)pp, *(const float4*)(pp + 4));
      }
#pragma unroll
      for (int dt = 0; dt < 8; ++dt) {
        O[0][dt] = __builtin_amdgcn_mfma_f32_16x16x32_f16(pa[0], vb[dt], O[0][dt], 0, 0, 0);
        O[1][dt] = __builtin_amdgcn_mfma_f32_16x16x32_f16(pa[1], vb[dt], O[1][dt], 0, 0, 0);
      }
    }
    __builtin_amdgcn_s_barrier();
  }
#undef SSTAGE
  WAITVM(0);   // drain dummy wrap stage before LDS dealloc
  float invl[2][4];
#pragma unroll
  for (int mt = 0; mt < 2; ++mt)
#pragma unroll
    for (int r = 0; r < 4; ++r) {
      float x = lacc[mt][r];
      x += __shfl_xor(x, 1); x += __shfl_xor(x, 2);
      x += __shfl_xor(x, 4); x += __shfl_xor(x, 8);
      invl[mt][r] = 1.0f / x;
    }
#pragma unroll
  for (int mt = 0; mt < 2; ++mt)
#pragma unroll
    for (int dt = 0; dt < 8; ++dt)
#pragma unroll
      for (int r = 0; r < 4; ++r) {
        size_t idx = ((size_t)(h * NN + rowbase + mt * 16 + l4 * 4 + r)) * D + dt * 16 + l15;
        out[OUT2_OFF + idx] = out[idx] - O[mt][dt][r] * invl[mt][r];
      }
}

// ---------------- launch ----------------
extern "C" void kernel_launch(void* const* d_in, const int* in_sizes, int n_in,
                              void* d_out, int out_size, void* d_ws, size_t ws_size,
                              hipStream_t stream) {
  const float* q = (const float*)d_in[0];
  const float* k = (const float*)d_in[1];
  const float* v = (const float*)d_in[2];
  float* out = (float*)d_out;
  char* wsb = (char*)d_ws;

  // ws layout: khi | klo | vT | cs(double) | mask   (~71 MB total)
  _Float16* khi = (_Float16*)wsb;
  _Float16* klo = (_Float16*)(wsb + KV_HALF_BYTES);
  _Float16* vT  = (_Float16*)(wsb + 2 * KV_HALF_BYTES);
  double* csb   = (double*)(wsb + 3 * KV_HALF_BYTES);
  float* maskb  = (float*)(wsb + 3 * KV_HALF_BYTES + CSD_BYTES);

  (void)hipMemsetAsync(csb, 0, CSD_BYTES, stream);
  cvt_k_kernel<<<dim3((H * NN * D) / (8 * 256)), dim3(256), 0, stream>>>(k, khi, klo);
  cvt_vT_kernel<<<dim3(NN / 64, D / 64, H), dim3(256), 0, stream>>>(v, vT);
  rmask_kernel<<<dim3(H * G * NN / 256), dim3(256), 0, stream>>>(maskb);
  dense_kernel<<<dim3((NN / 128) * H), dim3(256), 0, stream>>>(q, khi, klo, vT, out, csb);
  topk_kernel<<<dim3(H * G), dim3(256), 0, stream>>>(csb, maskb);
  sparse_kernel<<<dim3((NN / 128) * H), dim3(256), 0, stream>>>(q, khi, vT, maskb, out);
}